// Round 1
// baseline (1748.386 us; speedup 1.0000x reference)
//
#include <hip/hip_runtime.h>
#include <math.h>

// Problem constants (fixed by the reference)
#define BB   2
#define TT   2048
#define CC   256          // DIM = HD = HV = K = V = 256, H = 1
#define NHH  2
#define BT   (BB*TT)      // 4096 rows
#define BTC  ((size_t)BT*CC)

// ---------------------------------------------------------------------------
// fp32 tiled GEMM: C[M,N] = A[M,K] @ B[K,N], row-major, M%64==0, N%64==0, K%16==0
// ---------------------------------------------------------------------------
__global__ __launch_bounds__(256) void gemm_f32(
    const float* __restrict__ A, const float* __restrict__ B,
    float* __restrict__ C, int M, int N, int K)
{
    __shared__ float As[16][64];
    __shared__ float Bs[16][64];
    const int tid = threadIdx.x;
    const int tx = tid & 15;       // 0..15 (col group)
    const int ty = tid >> 4;       // 0..15 (row group)
    const int brow = blockIdx.x * 64;
    const int bcol = blockIdx.y * 64;

    const int ar = tid >> 2;            // 0..63 A-tile row
    const int ac = (tid & 3) * 4;       // k offset {0,4,8,12}
    const int bkr = tid >> 4;           // 0..15 B-tile k row
    const int bc  = (tid & 15) * 4;     // col offset

    float acc[4][4];
#pragma unroll
    for (int i = 0; i < 4; i++)
#pragma unroll
        for (int j = 0; j < 4; j++) acc[i][j] = 0.f;

    for (int kb = 0; kb < K; kb += 16) {
        float4 av = *(const float4*)(A + (size_t)(brow + ar) * K + kb + ac);
        As[ac + 0][ar] = av.x; As[ac + 1][ar] = av.y;
        As[ac + 2][ar] = av.z; As[ac + 3][ar] = av.w;
        float4 bv = *(const float4*)(B + (size_t)(kb + bkr) * N + bcol + bc);
        *(float4*)&Bs[bkr][bc] = bv;
        __syncthreads();
#pragma unroll
        for (int kk = 0; kk < 16; kk++) {
            float4 a4 = *(const float4*)&As[kk][ty * 4];
            float4 b4 = *(const float4*)&Bs[kk][tx * 4];
            float aa[4] = {a4.x, a4.y, a4.z, a4.w};
            float bb_[4] = {b4.x, b4.y, b4.z, b4.w};
#pragma unroll
            for (int i = 0; i < 4; i++)
#pragma unroll
                for (int j = 0; j < 4; j++) acc[i][j] += aa[i] * bb_[j];
        }
        __syncthreads();
    }
#pragma unroll
    for (int i = 0; i < 4; i++) {
        float4 o = make_float4(acc[i][0], acc[i][1], acc[i][2], acc[i][3]);
        *(float4*)(C + (size_t)(brow + ty * 4 + i) * N + bcol + tx * 4) = o;
    }
}

// ---------------------------------------------------------------------------
// g / beta scalar projections: g = -exp(A_log)*softplus(x@Wa + dt_bias),
// beta_j = sigmoid(x@Wb_j). One wave per (b,t) row.
// ---------------------------------------------------------------------------
__global__ __launch_bounds__(64) void proj_scalars(
    const float* __restrict__ x, const float* __restrict__ Wb,
    const float* __restrict__ Wa, const float* __restrict__ A_log,
    const float* __restrict__ dt_bias,
    float* __restrict__ g_arr, float* __restrict__ beta_arr)
{
    const int row = blockIdx.x;
    const int lane = threadIdx.x;
    float4 xv = ((const float4*)(x + (size_t)row * CC))[lane];
    float4 wa = ((const float4*)Wa)[lane];
    float4 w0 = ((const float4*)Wb)[lane];
    float4 w1 = ((const float4*)(Wb + CC))[lane];
    float da = xv.x * wa.x + xv.y * wa.y + xv.z * wa.z + xv.w * wa.w;
    float d0 = xv.x * w0.x + xv.y * w0.y + xv.z * w0.z + xv.w * w0.w;
    float d1 = xv.x * w1.x + xv.y * w1.y + xv.z * w1.z + xv.w * w1.w;
#pragma unroll
    for (int m = 1; m < 64; m <<= 1) {
        da += __shfl_xor(da, m, 64);
        d0 += __shfl_xor(d0, m, 64);
        d1 += __shfl_xor(d1, m, 64);
    }
    if (lane == 0) {
        float sp_in = da + dt_bias[0];
        float sp = (sp_in > 20.f) ? sp_in : log1pf(expf(sp_in));
        g_arr[row] = -expf(A_log[0]) * sp;
        beta_arr[row * 2 + 0] = 1.f / (1.f + expf(-d0));
        beta_arr[row * 2 + 1] = 1.f / (1.f + expf(-d1));
    }
}

// ---------------------------------------------------------------------------
// Causal conv (CONV=4) + silu + optional per-row l2norm.
// grid.x = BT rows, grid.y = 5 streams {q, k0, k1, v0, v1}
// ---------------------------------------------------------------------------
__global__ __launch_bounds__(256) void conv_silu(
    const float* __restrict__ q_pre, const float* __restrict__ k_pre,
    const float* __restrict__ v_pre,
    const float* __restrict__ qw, const float* __restrict__ kw,
    const float* __restrict__ vw,
    float* __restrict__ qn, float* __restrict__ kn, float* __restrict__ vn)
{
    const int bt = blockIdx.x;
    const int s  = blockIdx.y;
    const int c  = threadIdx.x;
    const int t  = bt & (TT - 1);

    const float* pre; const float* w; float* out; bool donorm;
    if (s == 0)      { pre = q_pre;       w = qw;         out = qn + (size_t)bt * CC;            donorm = true;  }
    else if (s == 1) { pre = k_pre;       w = kw;         out = kn + ((size_t)bt * 2 + 0) * CC;  donorm = true;  }
    else if (s == 2) { pre = k_pre + BTC; w = kw + CC*4;  out = kn + ((size_t)bt * 2 + 1) * CC;  donorm = true;  }
    else if (s == 3) { pre = v_pre;       w = vw;         out = vn + ((size_t)bt * 2 + 0) * CC;  donorm = false; }
    else             { pre = v_pre + BTC; w = vw + CC*4;  out = vn + ((size_t)bt * 2 + 1) * CC;  donorm = false; }

    const float w0 = w[c * 4 + 0], w1 = w[c * 4 + 1], w2 = w[c * 4 + 2], w3 = w[c * 4 + 3];
    float acc = 0.f;
    if (t >= 3) acc += pre[(size_t)(bt - 3) * CC + c] * w0;
    if (t >= 2) acc += pre[(size_t)(bt - 2) * CC + c] * w1;
    if (t >= 1) acc += pre[(size_t)(bt - 1) * CC + c] * w2;
    acc += pre[(size_t)bt * CC + c] * w3;
    float val = acc / (1.f + expf(-acc));   // silu

    if (donorm) {
        float ss = val * val;
#pragma unroll
        for (int m = 1; m < 64; m <<= 1) ss += __shfl_xor(ss, m, 64);
        __shared__ float red[4];
        if ((c & 63) == 0) red[c >> 6] = ss;
        __syncthreads();
        float tot = red[0] + red[1] + red[2] + red[3];
        val *= rsqrtf(tot + 1e-6f);
    }
    out[c] = val;
}

// ---------------------------------------------------------------------------
// Sequential scan. Columns (v) are independent -> parallelize over B x v-tiles.
// 1 wave per block; VW=4 columns per wave; 16 lanes per column, each lane owns
// a 16-element d-segment of the state column in registers.
// ---------------------------------------------------------------------------
__global__ __launch_bounds__(64) void scan_kernel(
    const float* __restrict__ qn, const float* __restrict__ kn,
    const float* __restrict__ vn, const float* __restrict__ g_arr,
    const float* __restrict__ beta_arr, float* __restrict__ o_mid)
{
    const int blk = blockIdx.x;
    const int b  = blk >> 6;        // 64 col-blocks per batch (256/4)
    const int cb = blk & 63;
    const int lane = threadIdx.x;
    const int col = cb * 4 + (lane >> 4);
    const int dbase = (lane & 15) << 4;

    const float* qb = qn + (size_t)b * TT * CC;
    const float* kb = kn + (size_t)b * TT * 2 * CC;
    const float* vb = vn + (size_t)b * TT * 2 * CC;
    const float* gb = g_arr + (size_t)b * TT;
    const float* bbp = beta_arr + (size_t)b * TT * 2;

    float S[16];
#pragma unroll
    for (int i = 0; i < 16; i++) S[i] = 0.f;

    float k0[16], k1[16], qv[16], v0n, v1n, b0n, b1n, gn;
    {
        const float4* p0 = (const float4*)(kb + dbase);
        const float4* p1 = (const float4*)(kb + CC + dbase);
        const float4* pq = (const float4*)(qb + dbase);
#pragma unroll
        for (int i = 0; i < 4; i++) {
            float4 a = p0[i]; k0[4*i]=a.x; k0[4*i+1]=a.y; k0[4*i+2]=a.z; k0[4*i+3]=a.w;
            float4 c = p1[i]; k1[4*i]=c.x; k1[4*i+1]=c.y; k1[4*i+2]=c.z; k1[4*i+3]=c.w;
            float4 d = pq[i]; qv[4*i]=d.x; qv[4*i+1]=d.y; qv[4*i+2]=d.z; qv[4*i+3]=d.w;
        }
        v0n = vb[col]; v1n = vb[CC + col];
        b0n = bbp[0];  b1n = bbp[1];  gn = gb[0];
    }

    for (int t = 0; t < TT; t++) {
        float c0[16], c1[16], cq[16];
#pragma unroll
        for (int i = 0; i < 16; i++) { c0[i] = k0[i]; c1[i] = k1[i]; cq[i] = qv[i]; }
        const float v0 = v0n, v1 = v1n, be0 = b0n, be1 = b1n, g = gn;

        if (t + 1 < TT) {   // software prefetch of next step's operands
            const int tn = t + 1;
            const float4* p0 = (const float4*)(kb + ((size_t)tn * 2 + 0) * CC + dbase);
            const float4* p1 = (const float4*)(kb + ((size_t)tn * 2 + 1) * CC + dbase);
            const float4* pq = (const float4*)(qb + (size_t)tn * CC + dbase);
#pragma unroll
            for (int i = 0; i < 4; i++) {
                float4 a = p0[i]; k0[4*i]=a.x; k0[4*i+1]=a.y; k0[4*i+2]=a.z; k0[4*i+3]=a.w;
                float4 c = p1[i]; k1[4*i]=c.x; k1[4*i+1]=c.y; k1[4*i+2]=c.z; k1[4*i+3]=c.w;
                float4 d = pq[i]; qv[4*i]=d.x; qv[4*i+1]=d.y; qv[4*i+2]=d.z; qv[4*i+3]=d.w;
            }
            v0n = vb[((size_t)tn * 2 + 0) * CC + col];
            v1n = vb[((size_t)tn * 2 + 1) * CC + col];
            b0n = bbp[tn * 2 + 0]; b1n = bbp[tn * 2 + 1]; gn = gb[tn];
        }

        const float decay = __expf(g);
#pragma unroll
        for (int i = 0; i < 16; i++) S[i] *= decay;

        // j = 0: kS = k^T S ; S += beta*k*(v - kS)
        float pa = 0.f, pb = 0.f, pc = 0.f, pd = 0.f;
#pragma unroll
        for (int i = 0; i < 4; i++) {
            pa += c0[i] * S[i]; pb += c0[4+i] * S[4+i];
            pc += c0[8+i] * S[8+i]; pd += c0[12+i] * S[12+i];
        }
        float p = (pa + pb) + (pc + pd);
        p += __shfl_xor(p, 1, 64); p += __shfl_xor(p, 2, 64);
        p += __shfl_xor(p, 4, 64); p += __shfl_xor(p, 8, 64);
        float coef = be0 * (v0 - p);
#pragma unroll
        for (int i = 0; i < 16; i++) S[i] += c0[i] * coef;

        // j = 1
        pa = pb = pc = pd = 0.f;
#pragma unroll
        for (int i = 0; i < 4; i++) {
            pa += c1[i] * S[i]; pb += c1[4+i] * S[4+i];
            pc += c1[8+i] * S[8+i]; pd += c1[12+i] * S[12+i];
        }
        p = (pa + pb) + (pc + pd);
        p += __shfl_xor(p, 1, 64); p += __shfl_xor(p, 2, 64);
        p += __shfl_xor(p, 4, 64); p += __shfl_xor(p, 8, 64);
        coef = be1 * (v1 - p);
#pragma unroll
        for (int i = 0; i < 16; i++) S[i] += c1[i] * coef;

        // o = q^T S
        pa = pb = pc = pd = 0.f;
#pragma unroll
        for (int i = 0; i < 4; i++) {
            pa += cq[i] * S[i]; pb += cq[4+i] * S[4+i];
            pc += cq[8+i] * S[8+i]; pd += cq[12+i] * S[12+i];
        }
        p = (pa + pb) + (pc + pd);
        p += __shfl_xor(p, 1, 64); p += __shfl_xor(p, 2, 64);
        p += __shfl_xor(p, 4, 64); p += __shfl_xor(p, 8, 64);
        if ((lane & 15) == 0) o_mid[((size_t)b * TT + t) * CC + col] = p;
    }
}

// ---------------------------------------------------------------------------
// o = o * rsqrt(mean(o^2) + 1e-5) * o_norm_w * silu(gate); written into gate buf
// ---------------------------------------------------------------------------
__global__ __launch_bounds__(256) void norm_gate(
    const float* __restrict__ o_mid, float* __restrict__ gate,
    const float* __restrict__ onw)
{
    const int bt = blockIdx.x;
    const int c  = threadIdx.x;
    const float o = o_mid[(size_t)bt * CC + c];
    float ss = o * o;
#pragma unroll
    for (int m = 1; m < 64; m <<= 1) ss += __shfl_xor(ss, m, 64);
    __shared__ float red[4];
    if ((c & 63) == 0) red[c >> 6] = ss;
    __syncthreads();
    const float mean = (red[0] + red[1] + red[2] + red[3]) * (1.f / 256.f);
    const float scale = rsqrtf(mean + 1e-5f);
    const float gv = gate[(size_t)bt * CC + c];
    const float silu = gv / (1.f + expf(-gv));
    gate[(size_t)bt * CC + c] = o * scale * onw[c] * silu;
}

// ---------------------------------------------------------------------------
extern "C" void kernel_launch(void* const* d_in, const int* in_sizes, int n_in,
                              void* d_out, int out_size, void* d_ws, size_t ws_size,
                              hipStream_t stream)
{
    const float* x        = (const float*)d_in[0];
    const float* Wq       = (const float*)d_in[1];
    const float* Wk       = (const float*)d_in[2];
    const float* Wv       = (const float*)d_in[3];
    const float* Wb       = (const float*)d_in[4];
    const float* Wa       = (const float*)d_in[5];
    const float* A_log    = (const float*)d_in[6];
    const float* dt_bias  = (const float*)d_in[7];
    const float* q_conv_w = (const float*)d_in[8];
    const float* k_conv_w = (const float*)d_in[9];
    const float* v_conv_w = (const float*)d_in[10];
    const float* Wg       = (const float*)d_in[11];
    const float* o_norm_w = (const float*)d_in[12];
    const float* Wo       = (const float*)d_in[13];
    float* out = (float*)d_out;

    float* ws = (float*)d_ws;
    float* q_pre  = ws;                    // BTC
    float* k_pre  = ws + 1 * BTC;          // 2*BTC (j-major)
    float* v_pre  = ws + 3 * BTC;          // 2*BTC
    float* gate   = ws + 5 * BTC;          // BTC
    float* qn     = ws + 6 * BTC;          // BTC
    float* kn     = ws + 7 * BTC;          // 2*BTC  ((bt, j, c) layout)
    float* vn     = ws + 9 * BTC;          // 2*BTC
    float* o_mid  = ws + 11 * BTC;         // BTC
    float* g_arr  = ws + 12 * BTC;         // BT
    float* beta_a = g_arr + BT;            // 2*BT

    const dim3 gg(BT / 64, CC / 64), gb(256);
    // Projections
    gemm_f32<<<gg, gb, 0, stream>>>(x, Wq,            q_pre,        BT, CC, CC);
    gemm_f32<<<gg, gb, 0, stream>>>(x, Wk,            k_pre,        BT, CC, CC);
    gemm_f32<<<gg, gb, 0, stream>>>(x, Wk + CC * CC,  k_pre + BTC,  BT, CC, CC);
    gemm_f32<<<gg, gb, 0, stream>>>(x, Wv,            v_pre,        BT, CC, CC);
    gemm_f32<<<gg, gb, 0, stream>>>(x, Wv + CC * CC,  v_pre + BTC,  BT, CC, CC);
    gemm_f32<<<gg, gb, 0, stream>>>(x, Wg,            gate,         BT, CC, CC);
    proj_scalars<<<BT, 64, 0, stream>>>(x, Wb, Wa, A_log, dt_bias, g_arr, beta_a);
    // conv + silu (+ l2norm for q/k)
    conv_silu<<<dim3(BT, 5), 256, 0, stream>>>(q_pre, k_pre, v_pre,
                                               q_conv_w, k_conv_w, v_conv_w,
                                               qn, kn, vn);
    // sequential scan
    scan_kernel<<<BB * 64, 64, 0, stream>>>(qn, kn, vn, g_arr, beta_a, o_mid);
    // RMS-norm + gate
    norm_gate<<<BT, 256, 0, stream>>>(o_mid, gate, o_norm_w);
    // final projection
    gemm_f32<<<gg, gb, 0, stream>>>(gate, Wo, out, BT, CC, CC);
}

// Round 2
// 1347.314 us; speedup vs baseline: 1.2977x; 1.2977x over previous
//
#include <hip/hip_runtime.h>
#include <math.h>

// Problem constants (fixed by the reference)
#define BB   2
#define TT   2048
#define CC   256          // DIM = HD = HV = K = V = 256, H = 1
#define NHH  2
#define BT   (BB*TT)      // 4096 rows
#define BTC  ((size_t)BT*CC)

// ---------------------------------------------------------------------------
// fp32 tiled GEMM: C[M,N] = A[M,K] @ B[K,N], row-major, M%64==0, N%64==0, K%16==0
// ---------------------------------------------------------------------------
__global__ __launch_bounds__(256) void gemm_f32(
    const float* __restrict__ A, const float* __restrict__ B,
    float* __restrict__ C, int M, int N, int K)
{
    __shared__ float As[16][64];
    __shared__ float Bs[16][64];
    const int tid = threadIdx.x;
    const int tx = tid & 15;       // 0..15 (col group)
    const int ty = tid >> 4;       // 0..15 (row group)
    const int brow = blockIdx.x * 64;
    const int bcol = blockIdx.y * 64;

    const int ar = tid >> 2;            // 0..63 A-tile row
    const int ac = (tid & 3) * 4;       // k offset {0,4,8,12}
    const int bkr = tid >> 4;           // 0..15 B-tile k row
    const int bc  = (tid & 15) * 4;     // col offset

    float acc[4][4];
#pragma unroll
    for (int i = 0; i < 4; i++)
#pragma unroll
        for (int j = 0; j < 4; j++) acc[i][j] = 0.f;

    for (int kb = 0; kb < K; kb += 16) {
        float4 av = *(const float4*)(A + (size_t)(brow + ar) * K + kb + ac);
        As[ac + 0][ar] = av.x; As[ac + 1][ar] = av.y;
        As[ac + 2][ar] = av.z; As[ac + 3][ar] = av.w;
        float4 bv = *(const float4*)(B + (size_t)(kb + bkr) * N + bcol + bc);
        *(float4*)&Bs[bkr][bc] = bv;
        __syncthreads();
#pragma unroll
        for (int kk = 0; kk < 16; kk++) {
            float4 a4 = *(const float4*)&As[kk][ty * 4];
            float4 b4 = *(const float4*)&Bs[kk][tx * 4];
            float aa[4] = {a4.x, a4.y, a4.z, a4.w};
            float bb_[4] = {b4.x, b4.y, b4.z, b4.w};
#pragma unroll
            for (int i = 0; i < 4; i++)
#pragma unroll
                for (int j = 0; j < 4; j++) acc[i][j] += aa[i] * bb_[j];
        }
        __syncthreads();
    }
#pragma unroll
    for (int i = 0; i < 4; i++) {
        float4 o = make_float4(acc[i][0], acc[i][1], acc[i][2], acc[i][3]);
        *(float4*)(C + (size_t)(brow + ty * 4 + i) * N + bcol + tx * 4) = o;
    }
}

// ---------------------------------------------------------------------------
// g / beta scalar projections. Stores decay = exp(g) (pre-exponentiated).
// ---------------------------------------------------------------------------
__global__ __launch_bounds__(64) void proj_scalars(
    const float* __restrict__ x, const float* __restrict__ Wb,
    const float* __restrict__ Wa, const float* __restrict__ A_log,
    const float* __restrict__ dt_bias,
    float* __restrict__ dec_arr, float* __restrict__ beta_arr)
{
    const int row = blockIdx.x;
    const int lane = threadIdx.x;
    float4 xv = ((const float4*)(x + (size_t)row * CC))[lane];
    float4 wa = ((const float4*)Wa)[lane];
    float4 w0 = ((const float4*)Wb)[lane];
    float4 w1 = ((const float4*)(Wb + CC))[lane];
    float da = xv.x * wa.x + xv.y * wa.y + xv.z * wa.z + xv.w * wa.w;
    float d0 = xv.x * w0.x + xv.y * w0.y + xv.z * w0.z + xv.w * w0.w;
    float d1 = xv.x * w1.x + xv.y * w1.y + xv.z * w1.z + xv.w * w1.w;
#pragma unroll
    for (int m = 1; m < 64; m <<= 1) {
        da += __shfl_xor(da, m, 64);
        d0 += __shfl_xor(d0, m, 64);
        d1 += __shfl_xor(d1, m, 64);
    }
    if (lane == 0) {
        float sp_in = da + dt_bias[0];
        float sp = (sp_in > 20.f) ? sp_in : log1pf(expf(sp_in));
        float g = -expf(A_log[0]) * sp;
        dec_arr[row] = expf(g);
        beta_arr[row * 2 + 0] = 1.f / (1.f + expf(-d0));
        beta_arr[row * 2 + 1] = 1.f / (1.f + expf(-d1));
    }
}

// ---------------------------------------------------------------------------
// Causal conv (CONV=4) + silu + optional per-row l2norm.
// ---------------------------------------------------------------------------
__global__ __launch_bounds__(256) void conv_silu(
    const float* __restrict__ q_pre, const float* __restrict__ k_pre,
    const float* __restrict__ v_pre,
    const float* __restrict__ qw, const float* __restrict__ kw,
    const float* __restrict__ vw,
    float* __restrict__ qn, float* __restrict__ kn, float* __restrict__ vn)
{
    const int bt = blockIdx.x;
    const int s  = blockIdx.y;
    const int c  = threadIdx.x;
    const int t  = bt & (TT - 1);

    const float* pre; const float* w; float* out; bool donorm;
    if (s == 0)      { pre = q_pre;       w = qw;         out = qn + (size_t)bt * CC;            donorm = true;  }
    else if (s == 1) { pre = k_pre;       w = kw;         out = kn + ((size_t)bt * 2 + 0) * CC;  donorm = true;  }
    else if (s == 2) { pre = k_pre + BTC; w = kw + CC*4;  out = kn + ((size_t)bt * 2 + 1) * CC;  donorm = true;  }
    else if (s == 3) { pre = v_pre;       w = vw;         out = vn + ((size_t)bt * 2 + 0) * CC;  donorm = false; }
    else             { pre = v_pre + BTC; w = vw + CC*4;  out = vn + ((size_t)bt * 2 + 1) * CC;  donorm = false; }

    const float w0 = w[c * 4 + 0], w1 = w[c * 4 + 1], w2 = w[c * 4 + 2], w3 = w[c * 4 + 3];
    float acc = 0.f;
    if (t >= 3) acc += pre[(size_t)(bt - 3) * CC + c] * w0;
    if (t >= 2) acc += pre[(size_t)(bt - 2) * CC + c] * w1;
    if (t >= 1) acc += pre[(size_t)(bt - 1) * CC + c] * w2;
    acc += pre[(size_t)bt * CC + c] * w3;
    float val = acc / (1.f + expf(-acc));   // silu

    if (donorm) {
        float ss = val * val;
#pragma unroll
        for (int m = 1; m < 64; m <<= 1) ss += __shfl_xor(ss, m, 64);
        __shared__ float red[4];
        if ((c & 63) == 0) red[c >> 6] = ss;
        __syncthreads();
        float tot = red[0] + red[1] + red[2] + red[3];
        val *= rsqrtf(tot + 1e-6f);
    }
    out[c] = val;
}

// ---------------------------------------------------------------------------
// DPP-based sum over each 16-lane group; result in all 16 lanes.
// quad_perm[1,0,3,2]=0xB1 (xor1), quad_perm[2,3,0,1]=0x4E (xor2),
// row_ror:4=0x124, row_ror:8=0x128.
// ---------------------------------------------------------------------------
__device__ __forceinline__ float red16(float x) {
    x += __int_as_float(__builtin_amdgcn_update_dpp(0, __float_as_int(x), 0xB1, 0xF, 0xF, false));
    x += __int_as_float(__builtin_amdgcn_update_dpp(0, __float_as_int(x), 0x4E, 0xF, 0xF, false));
    x += __int_as_float(__builtin_amdgcn_update_dpp(0, __float_as_int(x), 0x124, 0xF, 0xF, false));
    x += __int_as_float(__builtin_amdgcn_update_dpp(0, __float_as_int(x), 0x128, 0xF, 0xF, false));
    return x;
}

__device__ __forceinline__ float dot16(const float4 K[4], const float S[16]) {
    float a = K[0].x*S[0]  + K[0].y*S[1]  + K[0].z*S[2]  + K[0].w*S[3];
    float b = K[1].x*S[4]  + K[1].y*S[5]  + K[1].z*S[6]  + K[1].w*S[7];
    float c = K[2].x*S[8]  + K[2].y*S[9]  + K[2].z*S[10] + K[2].w*S[11];
    float d = K[3].x*S[12] + K[3].y*S[13] + K[3].z*S[14] + K[3].w*S[15];
    return (a + b) + (c + d);
}

__device__ __forceinline__ void axpy16(float S[16], const float4 K[4], float c) {
#pragma unroll
    for (int i = 0; i < 4; i++) {
        S[4*i+0] += K[i].x * c; S[4*i+1] += K[i].y * c;
        S[4*i+2] += K[i].z * c; S[4*i+3] += K[i].w * c;
    }
}

__device__ __forceinline__ void step_fn(float S[16],
    const float4 K0[4], const float4 K1[4], const float4 Q[4],
    float v0, float v1, float dec, float be0, float be1,
    float* op, int lane)
{
#pragma unroll
    for (int i = 0; i < 16; i++) S[i] *= dec;

    float r0 = red16(dot16(K0, S));
    float c0 = be0 * (v0 - r0);
    axpy16(S, K0, c0);

    float r1 = red16(dot16(K1, S));
    float c1 = be1 * (v1 - r1);
    axpy16(S, K1, c1);

    float rq = red16(dot16(Q, S));
    if ((lane & 15) == 0) *op = rq;
}

// ---------------------------------------------------------------------------
// Sequential scan, explicit register ping-pong double buffer + DPP reduce.
// 1 wave per block; 4 columns per wave; 16 lanes per column, 16 d-elems/lane.
// ---------------------------------------------------------------------------
#define LOADX(X0,X1,XQ,Xv0,Xv1,Xd,Xb,tt) { \
    const size_t _o = (size_t)(tt) * 128; \
    X0[0]=k0b[_o+0]; X0[1]=k0b[_o+1]; X0[2]=k0b[_o+2]; X0[3]=k0b[_o+3]; \
    X1[0]=k1b[_o+0]; X1[1]=k1b[_o+1]; X1[2]=k1b[_o+2]; X1[3]=k1b[_o+3]; \
    const size_t _q = (size_t)(tt) * 64; \
    XQ[0]=qb[_q+0]; XQ[1]=qb[_q+1]; XQ[2]=qb[_q+2]; XQ[3]=qb[_q+3]; \
    Xv0 = vb[(size_t)(tt)*512]; Xv1 = vb[(size_t)(tt)*512+256]; \
    Xd = db[(tt)]; Xb = bbp[(tt)]; }

__global__ __launch_bounds__(64, 1) void scan_kernel(
    const float* __restrict__ qn, const float* __restrict__ kn,
    const float* __restrict__ vn, const float* __restrict__ dec_arr,
    const float* __restrict__ beta_arr, float* __restrict__ o_mid)
{
    const int blk = blockIdx.x;
    const int b   = blk >> 6;        // 64 col-blocks per batch (256/4)
    const int cb  = blk & 63;
    const int lane = threadIdx.x;
    const int col = cb * 4 + (lane >> 4);
    const int dbase = (lane & 15) << 4;

    const float4* qb  = (const float4*)(qn + (size_t)b * TT * CC + dbase);
    const float4* k0b = (const float4*)(kn + (size_t)b * TT * 2 * CC + dbase);
    const float4* k1b = (const float4*)(kn + (size_t)b * TT * 2 * CC + CC + dbase);
    const float*  vb  = vn + (size_t)b * TT * 2 * CC + col;
    const float*  db  = dec_arr + (size_t)b * TT;
    const float2* bbp = (const float2*)(beta_arr + (size_t)b * TT * 2);
    float* ob = o_mid + (size_t)b * TT * CC + col;

    float S[16];
#pragma unroll
    for (int i = 0; i < 16; i++) S[i] = 0.f;

    float4 A0[4], A1[4], AQ[4]; float Av0, Av1, Ad; float2 Ab;
    float4 B0[4], B1[4], BQ[4]; float Bv0, Bv1, Bd; float2 Bb;

    LOADX(A0, A1, AQ, Av0, Av1, Ad, Ab, 0)

    for (int t = 0; t < TT; t += 2) {
        LOADX(B0, B1, BQ, Bv0, Bv1, Bd, Bb, t + 1)
        step_fn(S, A0, A1, AQ, Av0, Av1, Ad, Ab.x, Ab.y, ob + (size_t)t * CC, lane);
        if (t + 2 < TT) {
            LOADX(A0, A1, AQ, Av0, Av1, Ad, Ab, t + 2)
        }
        step_fn(S, B0, B1, BQ, Bv0, Bv1, Bd, Bb.x, Bb.y, ob + (size_t)(t + 1) * CC, lane);
    }
}

// ---------------------------------------------------------------------------
// o = o * rsqrt(mean(o^2) + 1e-5) * o_norm_w * silu(gate); written into gate buf
// ---------------------------------------------------------------------------
__global__ __launch_bounds__(256) void norm_gate(
    const float* __restrict__ o_mid, float* __restrict__ gate,
    const float* __restrict__ onw)
{
    const int bt = blockIdx.x;
    const int c  = threadIdx.x;
    const float o = o_mid[(size_t)bt * CC + c];
    float ss = o * o;
#pragma unroll
    for (int m = 1; m < 64; m <<= 1) ss += __shfl_xor(ss, m, 64);
    __shared__ float red[4];
    if ((c & 63) == 0) red[c >> 6] = ss;
    __syncthreads();
    const float mean = (red[0] + red[1] + red[2] + red[3]) * (1.f / 256.f);
    const float scale = rsqrtf(mean + 1e-5f);
    const float gv = gate[(size_t)bt * CC + c];
    const float silu = gv / (1.f + expf(-gv));
    gate[(size_t)bt * CC + c] = o * scale * onw[c] * silu;
}

// ---------------------------------------------------------------------------
extern "C" void kernel_launch(void* const* d_in, const int* in_sizes, int n_in,
                              void* d_out, int out_size, void* d_ws, size_t ws_size,
                              hipStream_t stream)
{
    const float* x        = (const float*)d_in[0];
    const float* Wq       = (const float*)d_in[1];
    const float* Wk       = (const float*)d_in[2];
    const float* Wv       = (const float*)d_in[3];
    const float* Wb       = (const float*)d_in[4];
    const float* Wa       = (const float*)d_in[5];
    const float* A_log    = (const float*)d_in[6];
    const float* dt_bias  = (const float*)d_in[7];
    const float* q_conv_w = (const float*)d_in[8];
    const float* k_conv_w = (const float*)d_in[9];
    const float* v_conv_w = (const float*)d_in[10];
    const float* Wg       = (const float*)d_in[11];
    const float* o_norm_w = (const float*)d_in[12];
    const float* Wo       = (const float*)d_in[13];
    float* out = (float*)d_out;

    float* ws = (float*)d_ws;
    float* q_pre  = ws;                    // BTC
    float* k_pre  = ws + 1 * BTC;          // 2*BTC (j-major)
    float* v_pre  = ws + 3 * BTC;          // 2*BTC
    float* gate   = ws + 5 * BTC;          // BTC
    float* qn     = ws + 6 * BTC;          // BTC
    float* kn     = ws + 7 * BTC;          // 2*BTC  ((bt, j, c) layout)
    float* vn     = ws + 9 * BTC;          // 2*BTC
    float* o_mid  = ws + 11 * BTC;         // BTC
    float* dec_a  = ws + 12 * BTC;         // BT   (decay = exp(g))
    float* beta_a = dec_a + BT;            // 2*BT

    const dim3 gg(BT / 64, CC / 64), gb(256);
    // Projections
    gemm_f32<<<gg, gb, 0, stream>>>(x, Wq,            q_pre,        BT, CC, CC);
    gemm_f32<<<gg, gb, 0, stream>>>(x, Wk,            k_pre,        BT, CC, CC);
    gemm_f32<<<gg, gb, 0, stream>>>(x, Wk + CC * CC,  k_pre + BTC,  BT, CC, CC);
    gemm_f32<<<gg, gb, 0, stream>>>(x, Wv,            v_pre,        BT, CC, CC);
    gemm_f32<<<gg, gb, 0, stream>>>(x, Wv + CC * CC,  v_pre + BTC,  BT, CC, CC);
    gemm_f32<<<gg, gb, 0, stream>>>(x, Wg,            gate,         BT, CC, CC);
    proj_scalars<<<BT, 64, 0, stream>>>(x, Wb, Wa, A_log, dt_bias, dec_a, beta_a);
    // conv + silu (+ l2norm for q/k)
    conv_silu<<<dim3(BT, 5), 256, 0, stream>>>(q_pre, k_pre, v_pre,
                                               q_conv_w, k_conv_w, v_conv_w,
                                               qn, kn, vn);
    // sequential scan
    scan_kernel<<<BB * 64, 64, 0, stream>>>(qn, kn, vn, dec_a, beta_a, o_mid);
    // RMS-norm + gate
    norm_gate<<<BT, 256, 0, stream>>>(o_mid, gate, o_norm_w);
    // final projection
    gemm_f32<<<gg, gb, 0, stream>>>(gate, Wo, out, BT, CC, CC);
}

// Round 3
// 958.498 us; speedup vs baseline: 1.8241x; 1.4057x over previous
//
#include <hip/hip_runtime.h>
#include <math.h>

// Problem constants (fixed by the reference)
#define BB   2
#define TT   2048
#define CC   256          // DIM = HD = HV = K = V = 256, H = 1
#define BT   (BB*TT)      // 4096 rows
#define BTC  ((size_t)BT*CC)
#define LE   64           // expanded chunk length (32 timesteps x 2 heads)
#define LT   32           // timesteps per chunk
#define NCH  (TT/LT)      // 64 chunks per batch
#define TE   (2*TT)       // expanded sequence length

// ---------------------------------------------------------------------------
// fp32 tiled GEMM: C[M,N] = A[M,K] @ B[K,N]
// ---------------------------------------------------------------------------
__global__ __launch_bounds__(256) void gemm_f32(
    const float* __restrict__ A, const float* __restrict__ B,
    float* __restrict__ C, int M, int N, int K)
{
    __shared__ float As[16][64];
    __shared__ float Bs[16][64];
    const int tid = threadIdx.x;
    const int tx = tid & 15;
    const int ty = tid >> 4;
    const int brow = blockIdx.x * 64;
    const int bcol = blockIdx.y * 64;

    const int ar = tid >> 2;
    const int ac = (tid & 3) * 4;
    const int bkr = tid >> 4;
    const int bc  = (tid & 15) * 4;

    float acc[4][4];
#pragma unroll
    for (int i = 0; i < 4; i++)
#pragma unroll
        for (int j = 0; j < 4; j++) acc[i][j] = 0.f;

    for (int kb = 0; kb < K; kb += 16) {
        float4 av = *(const float4*)(A + (size_t)(brow + ar) * K + kb + ac);
        As[ac + 0][ar] = av.x; As[ac + 1][ar] = av.y;
        As[ac + 2][ar] = av.z; As[ac + 3][ar] = av.w;
        float4 bv = *(const float4*)(B + (size_t)(kb + bkr) * N + bcol + bc);
        *(float4*)&Bs[bkr][bc] = bv;
        __syncthreads();
#pragma unroll
        for (int kk = 0; kk < 16; kk++) {
            float4 a4 = *(const float4*)&As[kk][ty * 4];
            float4 b4 = *(const float4*)&Bs[kk][tx * 4];
            float aa[4] = {a4.x, a4.y, a4.z, a4.w};
            float bb_[4] = {b4.x, b4.y, b4.z, b4.w};
#pragma unroll
            for (int i = 0; i < 4; i++)
#pragma unroll
                for (int j = 0; j < 4; j++) acc[i][j] += aa[i] * bb_[j];
        }
        __syncthreads();
    }
#pragma unroll
    for (int i = 0; i < 4; i++) {
        float4 o = make_float4(acc[i][0], acc[i][1], acc[i][2], acc[i][3]);
        *(float4*)(C + (size_t)(brow + ty * 4 + i) * N + bcol + tx * 4) = o;
    }
}

// ---------------------------------------------------------------------------
// g / beta scalar projections. Stores g (log-decay) and beta.
// ---------------------------------------------------------------------------
__global__ __launch_bounds__(64) void proj_scalars(
    const float* __restrict__ x, const float* __restrict__ Wb,
    const float* __restrict__ Wa, const float* __restrict__ A_log,
    const float* __restrict__ dt_bias,
    float* __restrict__ g_arr, float* __restrict__ beta_arr)
{
    const int row = blockIdx.x;
    const int lane = threadIdx.x;
    float4 xv = ((const float4*)(x + (size_t)row * CC))[lane];
    float4 wa = ((const float4*)Wa)[lane];
    float4 w0 = ((const float4*)Wb)[lane];
    float4 w1 = ((const float4*)(Wb + CC))[lane];
    float da = xv.x * wa.x + xv.y * wa.y + xv.z * wa.z + xv.w * wa.w;
    float d0 = xv.x * w0.x + xv.y * w0.y + xv.z * w0.z + xv.w * w0.w;
    float d1 = xv.x * w1.x + xv.y * w1.y + xv.z * w1.z + xv.w * w1.w;
#pragma unroll
    for (int m = 1; m < 64; m <<= 1) {
        da += __shfl_xor(da, m, 64);
        d0 += __shfl_xor(d0, m, 64);
        d1 += __shfl_xor(d1, m, 64);
    }
    if (lane == 0) {
        float sp_in = da + dt_bias[0];
        float sp = (sp_in > 20.f) ? sp_in : log1pf(expf(sp_in));
        g_arr[row] = -expf(A_log[0]) * sp;
        beta_arr[row * 2 + 0] = 1.f / (1.f + expf(-d0));
        beta_arr[row * 2 + 1] = 1.f / (1.f + expf(-d1));
    }
}

// ---------------------------------------------------------------------------
// Causal conv (CONV=4) + silu + optional per-row l2norm.
// ---------------------------------------------------------------------------
__global__ __launch_bounds__(256) void conv_silu(
    const float* __restrict__ q_pre, const float* __restrict__ k_pre,
    const float* __restrict__ v_pre,
    const float* __restrict__ qw, const float* __restrict__ kw,
    const float* __restrict__ vw,
    float* __restrict__ qn, float* __restrict__ kn, float* __restrict__ vn)
{
    const int bt = blockIdx.x;
    const int s  = blockIdx.y;
    const int c  = threadIdx.x;
    const int t  = bt & (TT - 1);

    const float* pre; const float* w; float* out; bool donorm;
    if (s == 0)      { pre = q_pre;       w = qw;         out = qn + (size_t)bt * CC;            donorm = true;  }
    else if (s == 1) { pre = k_pre;       w = kw;         out = kn + ((size_t)bt * 2 + 0) * CC;  donorm = true;  }
    else if (s == 2) { pre = k_pre + BTC; w = kw + CC*4;  out = kn + ((size_t)bt * 2 + 1) * CC;  donorm = true;  }
    else if (s == 3) { pre = v_pre;       w = vw;         out = vn + ((size_t)bt * 2 + 0) * CC;  donorm = false; }
    else             { pre = v_pre + BTC; w = vw + CC*4;  out = vn + ((size_t)bt * 2 + 1) * CC;  donorm = false; }

    const float w0 = w[c * 4 + 0], w1 = w[c * 4 + 1], w2 = w[c * 4 + 2], w3 = w[c * 4 + 3];
    float acc = 0.f;
    if (t >= 3) acc += pre[(size_t)(bt - 3) * CC + c] * w0;
    if (t >= 2) acc += pre[(size_t)(bt - 2) * CC + c] * w1;
    if (t >= 1) acc += pre[(size_t)(bt - 1) * CC + c] * w2;
    acc += pre[(size_t)bt * CC + c] * w3;
    float val = acc / (1.f + expf(-acc));   // silu

    if (donorm) {
        float ss = val * val;
#pragma unroll
        for (int m = 1; m < 64; m <<= 1) ss += __shfl_xor(ss, m, 64);
        __shared__ float red[4];
        if ((c & 63) == 0) red[c >> 6] = ss;
        __syncthreads();
        float tot = red[0] + red[1] + red[2] + red[3];
        val *= rsqrtf(tot + 1e-6f);
    }
    out[c] = val;
}

// ---------------------------------------------------------------------------
// chunk_pre: per (chunk, batch) block. Computes A = tril(b_i e^{gc_i-gc_j} k_i.k_j),
// solves (I+A)[Wm|U_loc] = [(bD)K | bV] by per-column forward substitution,
// computes Mq (masked decay-weighted q.k), and meta factors.
// Dynamic LDS: Kl[64][260] | Al[64][65] | Cr(max(Ql[32][260], Xs[64][260])) | gcl,bl,Dl
// ---------------------------------------------------------------------------
__global__ __launch_bounds__(256) void chunk_pre(
    const float* __restrict__ qn, const float* __restrict__ kn,
    const float* __restrict__ vn, const float* __restrict__ g_arr,
    const float* __restrict__ beta_arr,
    float* __restrict__ cWm, float* __restrict__ cUl,
    float* __restrict__ cMq, float* __restrict__ cMeta)
{
    extern __shared__ float sm[];
    float* Kl  = sm;              // [64][260]
    float* Al  = sm + 16640;      // [64][65]
    float* Cr  = sm + 20800;      // region C
    float* gcl = sm + 37440;
    float* bl  = sm + 37504;
    float* Dl  = sm + 37568;

    const int tid = threadIdx.x;
    const int ch = blockIdx.x, b = blockIdx.y;
    const size_t cb = (size_t)b * NCH + ch;
    const float* kg = kn + ((size_t)b * TE + (size_t)ch * LE) * CC;
    const float* vg = vn + ((size_t)b * TE + (size_t)ch * LE) * CC;
    const float* qg = qn + ((size_t)b * TT + (size_t)ch * LT) * CC;

    // stage K (64x256) into Kl (row stride 260 floats = 65 float4s, odd -> spread banks)
    {
        const int r0 = (tid >> 6) * 16;
        const int k4 = (tid & 63) * 4;
#pragma unroll
        for (int m = 0; m < 16; m++) {
            float4 v = *(const float4*)(kg + (size_t)(r0 + m) * CC + k4);
            *(float4*)(Kl + (r0 + m) * 260 + k4) = v;
        }
    }
    if (tid < 64) {
        bl[tid] = beta_arr[(size_t)b * TE + (size_t)ch * LE + tid];
        Dl[tid] = (tid & 1) ? 0.f : g_arr[(size_t)b * TT + (size_t)ch * LT + (tid >> 1)];
    }
    __syncthreads();
    if (tid == 0) {
        float s = 0.f;
        for (int u = 0; u < 64; u++) { s += Dl[u]; gcl[u] = s; }
    }
    __syncthreads();
    if (tid < 64) Dl[tid] = expf(gcl[tid]);

    // A tiles: thread (ti,tj): rows {ti+16m}, cols {tj+16m}
    {
        const int ti = tid >> 4, tj = tid & 15;
        float4 acc[4][4];
#pragma unroll
        for (int a = 0; a < 4; a++)
#pragma unroll
            for (int c2 = 0; c2 < 4; c2++) acc[a][c2] = make_float4(0.f,0.f,0.f,0.f);
        for (int k4 = 0; k4 < 256; k4 += 4) {
            float4 av[4], bv[4];
#pragma unroll
            for (int m = 0; m < 4; m++) av[m] = *(const float4*)(Kl + (ti + 16*m)*260 + k4);
#pragma unroll
            for (int m = 0; m < 4; m++) bv[m] = *(const float4*)(Kl + (tj + 16*m)*260 + k4);
#pragma unroll
            for (int a = 0; a < 4; a++)
#pragma unroll
                for (int c2 = 0; c2 < 4; c2++) {
                    acc[a][c2].x += av[a].x * bv[c2].x;
                    acc[a][c2].y += av[a].y * bv[c2].y;
                    acc[a][c2].z += av[a].z * bv[c2].z;
                    acc[a][c2].w += av[a].w * bv[c2].w;
                }
        }
#pragma unroll
        for (int a = 0; a < 4; a++)
#pragma unroll
            for (int c2 = 0; c2 < 4; c2++) {
                int i = ti + 16*a, j = tj + 16*c2;
                float d = acc[a][c2].x + acc[a][c2].y + acc[a][c2].z + acc[a][c2].w;
                Al[i*65 + j] = (j < i) ? bl[i] * expf(gcl[i] - gcl[j]) * d : 0.f;
            }
    }
    // stage Q (32 rows) into Cr
    {
        const int r0 = (tid >> 6) * 8;
        const int k4 = (tid & 63) * 4;
#pragma unroll
        for (int m = 0; m < 8; m++) {
            float4 v = *(const float4*)(qg + (size_t)(r0 + m) * CC + k4);
            *(float4*)(Cr + (r0 + m) * 260 + k4) = v;
        }
    }
    __syncthreads();
    // Mq tiles: rows {tr+16m, m<2} (q-row index r -> expanded i=2r+1), cols {tj+16m, m<4}
    {
        const int tr = tid >> 4, tj = tid & 15;
        float4 acc[2][4];
#pragma unroll
        for (int a = 0; a < 2; a++)
#pragma unroll
            for (int c2 = 0; c2 < 4; c2++) acc[a][c2] = make_float4(0.f,0.f,0.f,0.f);
        for (int k4 = 0; k4 < 256; k4 += 4) {
            float4 av[2], bv[4];
#pragma unroll
            for (int m = 0; m < 2; m++) av[m] = *(const float4*)(Cr + (tr + 16*m)*260 + k4);
#pragma unroll
            for (int m = 0; m < 4; m++) bv[m] = *(const float4*)(Kl + (tj + 16*m)*260 + k4);
#pragma unroll
            for (int a = 0; a < 2; a++)
#pragma unroll
                for (int c2 = 0; c2 < 4; c2++) {
                    acc[a][c2].x += av[a].x * bv[c2].x;
                    acc[a][c2].y += av[a].y * bv[c2].y;
                    acc[a][c2].z += av[a].z * bv[c2].z;
                    acc[a][c2].w += av[a].w * bv[c2].w;
                }
        }
#pragma unroll
        for (int a = 0; a < 2; a++)
#pragma unroll
            for (int c2 = 0; c2 < 4; c2++) {
                int r = tr + 16*a, j = tj + 16*c2, i = 2*r + 1;
                float d = acc[a][c2].x + acc[a][c2].y + acc[a][c2].z + acc[a][c2].w;
                cMq[(cb*32 + r)*64 + j] = (j <= i) ? d * expf(gcl[i] - gcl[j]) : 0.f;
            }
    }
    // meta: [0:32]=D at odd rows, [32:96]=Ks[j]=exp(gc63-gcj), [96]=D63
    if (tid < 32)                cMeta[cb*128 + tid] = Dl[2*tid + 1];
    if (tid >= 32 && tid < 96)   cMeta[cb*128 + tid] = expf(gcl[63] - gcl[tid - 32]);
    if (tid == 96)               cMeta[cb*128 + 96]  = Dl[63];
    __syncthreads();   // Cr (Ql) free; Al final

    float* Xs = Cr;   // [64][260], one column per thread (thread-private)
    // ---- strip K: RHS = (b*D) .* K  -> Wm
    for (int i = 0; i < 64; i++) Xs[i*260 + tid] = bl[i] * Dl[i] * Kl[i*260 + tid];
    for (int i = 1; i < 64; i++) {
        float a2 = Xs[i*260 + tid];
        const float* arow = Al + i*65;
        for (int j = 0; j < i; j++) a2 -= arow[j] * Xs[j*260 + tid];
        Xs[i*260 + tid] = a2;
    }
    {
        float* Wg = cWm + cb * (size_t)(LE*CC);
        for (int i = 0; i < 64; i++) Wg[(size_t)i*CC + tid] = Xs[i*260 + tid];
    }
    // ---- strip V: RHS = b .* V  -> U_loc
    for (int i = 0; i < 64; i++) Xs[i*260 + tid] = bl[i] * vg[(size_t)i*CC + tid];
    for (int i = 1; i < 64; i++) {
        float a2 = Xs[i*260 + tid];
        const float* arow = Al + i*65;
        for (int j = 0; j < i; j++) a2 -= arow[j] * Xs[j*260 + tid];
        Xs[i*260 + tid] = a2;
    }
    {
        float* Ug = cUl + cb * (size_t)(LE*CC);
        for (int i = 0; i < 64; i++) Ug[(size_t)i*CC + tid] = Xs[i*260 + tid];
    }
}

// ---------------------------------------------------------------------------
// chain: sequential over chunks; each block owns 4 columns of state S (in LDS).
// Per chunk: X = U_loc - Wm @ S ; O = D_odd*(Q@S) + Mq @ X ; S = D_L*S + Kg^T @ X
// (Kg built on the fly from kn rows * Ks scale folded into X.)
// ---------------------------------------------------------------------------
__global__ __launch_bounds__(256) void chain_kernel(
    const float* __restrict__ qn, const float* __restrict__ kn,
    const float* __restrict__ cWm, const float* __restrict__ cUl,
    const float* __restrict__ cMq, const float* __restrict__ cMeta,
    float* __restrict__ o_mid)
{
    extern __shared__ float sm[];
    float*  Wl     = sm;            // [64][260]
    float*  Sl     = sm + 16640;    // [4][256]   S[c][d]
    float4* Xs4    = (float4*)(sm + 17664); // [64] scaled X (by Ks)
    float*  Xu     = sm + 17920;    // [64][4] unscaled X
    float4* Yp4    = (float4*)(sm + 18176); // [4][64] partials
    float*  Mql    = sm + 19200;    // [32][66]
    float*  meta_l = sm + 21312;    // [128]
    float*  qsum   = sm + 21440;    // [256]

    const int tid = threadIdx.x;
    const int b = blockIdx.y;
    const int col0 = blockIdx.x * 4;

#pragma unroll
    for (int c2 = 0; c2 < 4; c2++) Sl[c2*256 + tid] = 0.f;

    for (int ch = 0; ch < NCH; ch++) {
        const size_t cb = (size_t)b * NCH + ch;
        // ---- stage Wm, Mq, meta
        {
            const float* Wg = cWm + cb * (size_t)(LE*CC);
            const int r0 = (tid >> 6) * 16;
            const int k4 = (tid & 63) * 4;
#pragma unroll
            for (int m = 0; m < 16; m++)
                *(float4*)(Wl + (r0 + m)*260 + k4) = *(const float4*)(Wg + (size_t)(r0 + m)*CC + k4);
            const float* Mg = cMq + cb * (size_t)(32*64);
#pragma unroll
            for (int p = 0; p < 8; p++) {
                int idx = tid + p*256;
                Mql[(idx >> 6)*66 + (idx & 63)] = Mg[idx];
            }
            if (tid < 128) meta_l[tid] = cMeta[cb*128 + tid];
        }
        __syncthreads();
        // ---- phase 1: Y partials (thread = (j, k-segment))
        {
            const int j = tid & 63, ks = tid >> 6;
            float4 pp[4];
#pragma unroll
            for (int c2 = 0; c2 < 4; c2++) pp[c2] = make_float4(0.f,0.f,0.f,0.f);
            const int kbeg = ks * 64;
            for (int k4 = kbeg; k4 < kbeg + 64; k4 += 4) {
                float4 w = *(const float4*)(Wl + j*260 + k4);
#pragma unroll
                for (int c2 = 0; c2 < 4; c2++) {
                    float4 s4 = *(const float4*)(Sl + c2*256 + k4);
                    pp[c2].x += w.x*s4.x; pp[c2].y += w.y*s4.y;
                    pp[c2].z += w.z*s4.z; pp[c2].w += w.w*s4.w;
                }
            }
            float4 yo;
            yo.x = pp[0].x + pp[0].y + pp[0].z + pp[0].w;
            yo.y = pp[1].x + pp[1].y + pp[1].z + pp[1].w;
            yo.z = pp[2].x + pp[2].y + pp[2].z + pp[2].w;
            yo.w = pp[3].x + pp[3].y + pp[3].z + pp[3].w;
            Yp4[ks*64 + j] = yo;
        }
        __syncthreads();
        // ---- phase 1b: X = U_loc - Y ; store scaled / unscaled
        if (tid < 64) {
            float4 y0 = Yp4[tid], y1 = Yp4[64+tid], y2 = Yp4[128+tid], y3 = Yp4[192+tid];
            float4 y; y.x = y0.x+y1.x+y2.x+y3.x; y.y = y0.y+y1.y+y2.y+y3.y;
            y.z = y0.z+y1.z+y2.z+y3.z; y.w = y0.w+y1.w+y2.w+y3.w;
            const float* Ug = cUl + cb * (size_t)(LE*CC);
            float4 u = *(const float4*)(Ug + (size_t)tid*CC + col0);
            float4 x; x.x = u.x - y.x; x.y = u.y - y.y; x.z = u.z - y.z; x.w = u.w - y.w;
            Xu[tid*4+0] = x.x; Xu[tid*4+1] = x.y; Xu[tid*4+2] = x.z; Xu[tid*4+3] = x.w;
            float ksc = meta_l[32 + tid];
            float4 xs; xs.x = x.x*ksc; xs.y = x.y*ksc; xs.z = x.z*ksc; xs.w = x.w*ksc;
            Xs4[tid] = xs;
        }
        __syncthreads();
        // ---- phase 2a: QS partial dots
        const int r = tid & 31, cc = (tid >> 5) & 3, h = tid >> 7;
        {
            const float* qrow = qn + ((size_t)b*TT + (size_t)ch*LT + r)*CC + h*128;
            float acc = 0.f;
            for (int k4 = 0; k4 < 128; k4 += 4) {
                float4 qv = *(const float4*)(qrow + k4);
                float4 sv = *(const float4*)(Sl + cc*256 + h*128 + k4);
                acc += qv.x*sv.x + qv.y*sv.y + qv.z*sv.z + qv.w*sv.w;
            }
            qsum[tid] = acc;
        }
        __syncthreads();
        // ---- phase 2b: O rows (tid<128) ; phase 3: S update (all threads)
        if (tid < 128) {
            float qs = qsum[tid] + qsum[tid + 128];
            float o = meta_l[r] * qs;
            const float* mrow = Mql + r*66;
            for (int j2 = 0; j2 < 64; j2++) o += mrow[j2] * Xu[j2*4 + cc];
            o_mid[((size_t)b*TT + (size_t)ch*LT + r)*CC + col0 + cc] = o;
        }
        {
            const float DL = meta_l[96];
            float s0 = DL * Sl[0*256 + tid];
            float s1 = DL * Sl[1*256 + tid];
            float s2 = DL * Sl[2*256 + tid];
            float s3 = DL * Sl[3*256 + tid];
            const float* kgc = kn + ((size_t)b*TE + (size_t)ch*LE)*CC + tid;
#pragma unroll 8
            for (int j2 = 0; j2 < 64; j2++) {
                float kv = kgc[(size_t)j2*CC];
                float4 xs = Xs4[j2];
                s0 += kv*xs.x; s1 += kv*xs.y; s2 += kv*xs.z; s3 += kv*xs.w;
            }
            Sl[0*256 + tid] = s0; Sl[1*256 + tid] = s1;
            Sl[2*256 + tid] = s2; Sl[3*256 + tid] = s3;
        }
        __syncthreads();
    }
}

// ---------------------------------------------------------------------------
// o = o * rsqrt(mean(o^2) + 1e-5) * o_norm_w * silu(gate)
// ---------------------------------------------------------------------------
__global__ __launch_bounds__(256) void norm_gate(
    const float* __restrict__ o_mid, float* __restrict__ gate,
    const float* __restrict__ onw)
{
    const int bt = blockIdx.x;
    const int c  = threadIdx.x;
    const float o = o_mid[(size_t)bt * CC + c];
    float ss = o * o;
#pragma unroll
    for (int m = 1; m < 64; m <<= 1) ss += __shfl_xor(ss, m, 64);
    __shared__ float red[4];
    if ((c & 63) == 0) red[c >> 6] = ss;
    __syncthreads();
    const float mean = (red[0] + red[1] + red[2] + red[3]) * (1.f / 256.f);
    const float scale = rsqrtf(mean + 1e-5f);
    const float gv = gate[(size_t)bt * CC + c];
    const float silu = gv / (1.f + expf(-gv));
    gate[(size_t)bt * CC + c] = o * scale * onw[c] * silu;
}

// ---------------------------------------------------------------------------
extern "C" void kernel_launch(void* const* d_in, const int* in_sizes, int n_in,
                              void* d_out, int out_size, void* d_ws, size_t ws_size,
                              hipStream_t stream)
{
    const float* x        = (const float*)d_in[0];
    const float* Wq       = (const float*)d_in[1];
    const float* Wk       = (const float*)d_in[2];
    const float* Wv       = (const float*)d_in[3];
    const float* Wb       = (const float*)d_in[4];
    const float* Wa       = (const float*)d_in[5];
    const float* A_log    = (const float*)d_in[6];
    const float* dt_bias  = (const float*)d_in[7];
    const float* q_conv_w = (const float*)d_in[8];
    const float* k_conv_w = (const float*)d_in[9];
    const float* v_conv_w = (const float*)d_in[10];
    const float* Wg       = (const float*)d_in[11];
    const float* o_norm_w = (const float*)d_in[12];
    const float* Wo       = (const float*)d_in[13];
    float* out = (float*)d_out;

    float* ws = (float*)d_ws;
    float* q_pre  = ws;                    // BTC
    float* k_pre  = ws + 1 * BTC;          // 2*BTC
    float* v_pre  = ws + 3 * BTC;          // 2*BTC
    float* gate   = ws + 5 * BTC;          // BTC
    float* qn     = ws + 6 * BTC;          // BTC
    float* kn     = ws + 7 * BTC;          // 2*BTC (expanded (b,u,c))
    float* vn     = ws + 9 * BTC;          // 2*BTC
    float* o_mid  = ws + 11 * BTC;         // BTC
    float* g_arr  = ws + 12 * BTC;         // BT
    float* beta_a = g_arr + BT;            // 2*BT
    float* cWm    = beta_a + 2 * (size_t)BT;             // 128*64*256
    float* cUl    = cWm + (size_t)BB*NCH*LE*CC;          // 128*64*256
    float* cMq    = cUl + (size_t)BB*NCH*LE*CC;          // 128*32*64
    float* cMeta  = cMq + (size_t)BB*NCH*32*64;          // 128*128

    const int PRE_LDS = 37632 * 4;   // 150528 B
    const int CHN_LDS = 21696 * 4;   // 86784 B
    hipFuncSetAttribute(reinterpret_cast<const void*>(chunk_pre),
                        hipFuncAttributeMaxDynamicSharedMemorySize, PRE_LDS);
    hipFuncSetAttribute(reinterpret_cast<const void*>(chain_kernel),
                        hipFuncAttributeMaxDynamicSharedMemorySize, CHN_LDS);

    const dim3 gg(BT / 64, CC / 64), gb(256);
    gemm_f32<<<gg, gb, 0, stream>>>(x, Wq,            q_pre,        BT, CC, CC);
    gemm_f32<<<gg, gb, 0, stream>>>(x, Wk,            k_pre,        BT, CC, CC);
    gemm_f32<<<gg, gb, 0, stream>>>(x, Wk + CC * CC,  k_pre + BTC,  BT, CC, CC);
    gemm_f32<<<gg, gb, 0, stream>>>(x, Wv,            v_pre,        BT, CC, CC);
    gemm_f32<<<gg, gb, 0, stream>>>(x, Wv + CC * CC,  v_pre + BTC,  BT, CC, CC);
    gemm_f32<<<gg, gb, 0, stream>>>(x, Wg,            gate,         BT, CC, CC);
    proj_scalars<<<BT, 64, 0, stream>>>(x, Wb, Wa, A_log, dt_bias, g_arr, beta_a);
    conv_silu<<<dim3(BT, 5), 256, 0, stream>>>(q_pre, k_pre, v_pre,
                                               q_conv_w, k_conv_w, v_conv_w,
                                               qn, kn, vn);
    chunk_pre<<<dim3(NCH, BB), 256, PRE_LDS, stream>>>(qn, kn, vn, g_arr, beta_a,
                                                       cWm, cUl, cMq, cMeta);
    chain_kernel<<<dim3(CC/4, BB), 256, CHN_LDS, stream>>>(qn, kn, cWm, cUl, cMq, cMeta, o_mid);
    norm_gate<<<BT, 256, 0, stream>>>(o_mid, gate, o_norm_w);
    gemm_f32<<<gg, gb, 0, stream>>>(gate, Wo, out, BT, CC, CC);
}